// Round 8
// baseline (1570.174 us; speedup 1.0000x reference)
//
#include <hip/hip_runtime.h>
#include <hip/hip_bf16.h>

#define N_STORE 100000
#define N_DEPT  20000
#define F_IN    128

using u16    = unsigned short;
using bf16x8 = __attribute__((ext_vector_type(8))) __bf16;
using f32x4  = __attribute__((ext_vector_type(4))) float;

__device__ __forceinline__ float b2f(u16 x) {
    unsigned u = ((unsigned)x) << 16;
    return __builtin_bit_cast(float, u);
}
__device__ __forceinline__ u16 f2b(float f) {
    unsigned u = __builtin_bit_cast(unsigned, f);
    u += 0x7FFFu + ((u >> 16) & 1u);   // round-to-nearest-even
    return (u16)(u >> 16);
}

// ---------------- CSR build (edges: int32, block [src(E); dst(E)], dict slots — HW-verified r7) ----
__global__ void k_zeroi(int* p, int n) {
    int i = blockIdx.x * 256 + threadIdx.x;
    if (i < n) p[i] = 0;
}

__global__ void k_hist(const int* __restrict__ e, int E, int n, int* __restrict__ counts) {
    int i = blockIdx.x * 256 + threadIdx.x;
    if (i >= E) return;
    int d = e[E + i];
    if (d >= 0 && d < n) atomicAdd(&counts[d], 1);
}

__global__ void k_scan1(const int* __restrict__ counts, int n,
                        int* __restrict__ incl, int* __restrict__ partials) {
    __shared__ int s[256];
    int t = threadIdx.x, i = blockIdx.x * 256 + t;
    int v = (i < n) ? counts[i] : 0;
    s[t] = v; __syncthreads();
    for (int o = 1; o < 256; o <<= 1) {
        int u = (t >= o) ? s[t - o] : 0;
        __syncthreads();
        s[t] += u;
        __syncthreads();
    }
    if (i < n) incl[i] = s[t];
    if (t == 255) partials[blockIdx.x] = s[255];
}

__global__ void k_scan2(int* partials, int nb) {
    __shared__ int s[512];
    int t = threadIdx.x;
    int v = (t < nb) ? partials[t] : 0;
    s[t] = v; __syncthreads();
    for (int o = 1; o < 512; o <<= 1) {
        int u = (t >= o) ? s[t - o] : 0;
        __syncthreads();
        s[t] += u;
        __syncthreads();
    }
    if (t < nb) partials[t] = s[t];
}

__global__ void k_scan3(const int* __restrict__ counts, const int* __restrict__ incl,
                        const int* __restrict__ partials, int n, int total,
                        int* __restrict__ offs, int* __restrict__ cursor) {
    int i = blockIdx.x * 256 + threadIdx.x;
    if (i < n) {
        int base = blockIdx.x ? partials[blockIdx.x - 1] : 0;
        int e = base + incl[i] - counts[i];
        offs[i] = e;
        cursor[i] = e;
    } else if (i == n) {
        offs[n] = total;
    }
}

__global__ void k_scatter(const int* __restrict__ e, int E, int n,
                          int* __restrict__ cursor, int* __restrict__ srcs_sorted) {
    int i = blockIdx.x * 256 + threadIdx.x;
    if (i >= E) return;
    int d = e[E + i];
    if (d < 0 || d >= n) return;
    int pos = atomicAdd(&cursor[d], 1);
    srcs_sorted[pos] = e[i];
}

// ---------------- weight panel packing (MFMA B-fragment order), f32 -> bf16 ----
// B-frag: entry ((ct*KT+kt)*64+lane), elem j = B[k=kt*32+(lane>>4)*8+j][n=ct*16+(lane&15)]
// store panel cols: 0..63=W_s[0]; 64..127=W_s[2]; 128..131 fold(W_s[0],aS0);
//   132..135 fold(W_s[2],aS2); 136..139 fold(W_d[1],aD1); 140..143 fold(W_d[2],aD2)
__global__ void k_pack_store(const float* __restrict__ Wa, const float* __restrict__ Wb,
                             const float* __restrict__ Wd1, const float* __restrict__ Wd2,
                             const float* __restrict__ aS0, const float* __restrict__ aS2,
                             const float* __restrict__ aD1, const float* __restrict__ aD2,
                             int K, u16* __restrict__ out) {
    int id = blockIdx.x * 256 + threadIdx.x;
    int total = K * 144;
    if (id >= total) return;
    int k = id / 144, n = id - k * 144;
    float val;
    if (n < 64) val = Wa[k * 64 + n];
    else if (n < 128) val = Wb[k * 64 + (n - 64)];
    else {
        int g = (n - 128) >> 2, h = (n - 128) & 3;
        const float* W = (g == 0) ? Wa : (g == 1) ? Wb : (g == 2) ? Wd1 : Wd2;
        const float* a = (g == 0) ? aS0 : (g == 1) ? aS2 : (g == 2) ? aD1 : aD2;
        float acc = 0.f;
        for (int c = 0; c < 16; ++c) acc += W[k * 64 + h * 16 + c] * a[h * 16 + c];
        val = acc;
    }
    int KT = K >> 5;
    int ct = n >> 4, col = n & 15, kt = k >> 5, q = (k >> 3) & 3, j = k & 7;
    out[(size_t)((ct * KT + kt) * 64 + q * 16 + col) * 8 + j] = f2b(val);
}

// dept panel cols: 0..63=W_s[1]; 64..67 fold(W_d[0],aD0); 68..71 fold(W_s[1],aS1); 72..79 pad
__global__ void k_pack_dept(const float* __restrict__ Ws1, const float* __restrict__ Wd0,
                            const float* __restrict__ aD0, const float* __restrict__ aS1,
                            int K, u16* __restrict__ out) {
    int id = blockIdx.x * 256 + threadIdx.x;
    int total = K * 80;
    if (id >= total) return;
    int k = id / 80, n = id - k * 80;
    float val;
    if (n < 64) val = Ws1[k * 64 + n];
    else if (n < 72) {
        int g = (n - 64) >> 2, h = (n - 64) & 3;
        const float* W = g ? Ws1 : Wd0;
        const float* a = g ? aS1 : aD0;
        float acc = 0.f;
        for (int c = 0; c < 16; ++c) acc += W[k * 64 + h * 16 + c] * a[h * 16 + c];
        val = acc;
    } else val = 0.f;
    int KT = K >> 5;
    int ct = n >> 4, col = n & 15, kt = k >> 5, q = (k >> 3) & 3, j = k & 7;
    out[(size_t)((ct * KT + kt) * 64 + q * 16 + col) * 8 + j] = f2b(val);
}

// ---------------- GEMM: wave per 16-row stripe, bf16 out; CVT=1 reads f32 A ----
template <int KT, int CVT>
__global__ void k_gemm(const void* __restrict__ Ain, int nrows, int K,
                       const u16* __restrict__ Bpanel, int CT,
                       u16* __restrict__ C, int cstride) {
    int wid = (blockIdx.x * blockDim.x + threadIdx.x) >> 6;
    int lane = threadIdx.x & 63;
    int m0 = wid << 4;
    if (m0 >= nrows) return;
    int r = lane & 15, q = lane >> 4;   // A: row=lane&15, k=(lane>>4)*8+j
    bf16x8 a[KT];
    if (CVT) {
        const float* ap = (const float*)Ain + (size_t)(m0 + r) * K + q * 8;
#pragma unroll
        for (int kt = 0; kt < KT; ++kt) {
            f32x4 f0 = *(const f32x4*)(ap + kt * 32);
            f32x4 f1 = *(const f32x4*)(ap + kt * 32 + 4);
            bf16x8 v;
#pragma unroll
            for (int j = 0; j < 4; ++j) {
                v[j]     = __builtin_bit_cast(__bf16, f2b(f0[j]));
                v[4 + j] = __builtin_bit_cast(__bf16, f2b(f1[j]));
            }
            a[kt] = v;
        }
    } else {
        const u16* ap = (const u16*)Ain + (size_t)(m0 + r) * K + q * 8;
#pragma unroll
        for (int kt = 0; kt < KT; ++kt) a[kt] = *(const bf16x8*)(ap + kt * 32);
    }
    const bf16x8* B = (const bf16x8*)Bpanel;
    for (int ct = 0; ct < CT; ++ct) {
        f32x4 acc = {0.f, 0.f, 0.f, 0.f};
#pragma unroll
        for (int kt = 0; kt < KT; ++kt)
            acc = __builtin_amdgcn_mfma_f32_16x16x32_bf16(a[kt], B[(ct * KT + kt) * 64 + lane], acc, 0, 0, 0);
        // D: row=q*4+i, col=r -> C[m0+q*4+i][ct*16+r]
        u16* cp = C + (size_t)m0 * cstride + ct * 16 + r;
#pragma unroll
        for (int i = 0; i < 4; ++i) cp[(size_t)(q * 4 + i) * cstride] = f2b(acc[i]);
    }
}

// ---------------- GAT aggregation: one wave per dst node, 64 lanes = 64 channels ----
// mode 0: write partial (scale applied, no relu); mode 1: final write;
// mode 2: add stored partial then final write.  Target: fOut (f32, d_out) if non-null,
// else bOut (bf16 activations in ws).
__global__ void k_agg(const int* __restrict__ offs, const int* __restrict__ srcs, int ndst,
                      int nsrcmax,
                      const u16* __restrict__ srcTab, int sstride, int hsOff, int alsOff,
                      const u16* __restrict__ dstTab, int dstride, int aldOff,
                      const float* __restrict__ bias, float scale, int mode, int doRelu,
                      u16* __restrict__ bOut, float* __restrict__ fOut) {
    int wid = (blockIdx.x * blockDim.x + threadIdx.x) >> 6;
    if (wid >= ndst) return;
    int lane = threadIdx.x & 63, h = lane >> 4;
    float ald = b2f(dstTab[(size_t)wid * dstride + aldOff + h]);
    int j0 = offs[wid], j1 = offs[wid + 1];
    float acc = 0.f, den = 0.f;
    for (int j = j0; j < j1; ++j) {
        int src = srcs[j];
        src = (src < 0 || src >= nsrcmax) ? 0 : src;
        const u16* row = srcTab + (size_t)src * sstride;
        float e = b2f(row[alsOff + h]) + ald;
        e = (e > 0.f) ? e : 0.2f * e;
        float ex = __expf(e);
        acc = fmaf(ex, b2f(row[hsOff + lane]), acc);
        den += ex;
    }
    float out = (acc / (den + 1e-16f) + bias[lane]) * scale;
    size_t oi = (size_t)wid * 64 + lane;
    if (fOut) {
        if (mode == 2) out += fOut[oi];
        if (mode != 0 && doRelu) out = out > 0.f ? out : 0.f;
        fOut[oi] = out;                     // f32 final output (d_out is float*)
    } else {
        if (mode == 2) out += b2f(bOut[oi]);
        if (mode != 0 && doRelu) out = out > 0.f ? out : 0.f;
        bOut[oi] = f2b(out);                // bf16 inter-layer activation
    }
}

extern "C" void kernel_launch(void* const* d_in, const int* in_sizes, int n_in,
                              void* d_out, int out_size, void* d_ws, size_t ws_size,
                              hipStream_t stream) {
    const float* x_store = (const float*)d_in[0];
    const float* x_dept  = (const float*)d_in[1];
    const int* e_sd = (const int*)d_in[2];
    const int* e_ds = (const int*)d_in[3];
    const int* e_ss = (const int*)d_in[4];
    const float* W_src0  = (const float*)d_in[5];
    const float* W_dst0  = (const float*)d_in[6];
    const float* W_src_h = (const float*)d_in[7];
    const float* W_dst_h = (const float*)d_in[8];
    const float* att_src = (const float*)d_in[9];
    const float* att_dst = (const float*)d_in[10];
    const float* bias    = (const float*)d_in[11];
    const int E = in_sizes[2] / 2;

    // ---- workspace (~77 MB) ----
    char* w = (char*)d_ws;
    auto alloc = [&](size_t bytes) -> char* {
        char* p = w;
        w += (bytes + 255) & ~(size_t)255;
        return p;
    };
    int* off_sd  = (int*)alloc((size_t)(N_DEPT + 1) * 4);
    int* off_ds  = (int*)alloc((size_t)(N_STORE + 1) * 4);
    int* off_ss  = (int*)alloc((size_t)(N_STORE + 1) * 4);
    int* srcs_sd = (int*)alloc((size_t)E * 4);
    int* srcs_ds = (int*)alloc((size_t)E * 4);
    int* srcs_ss = (int*)alloc((size_t)E * 4);
    int* counts  = (int*)alloc((size_t)N_STORE * 4);
    int* incl    = (int*)alloc((size_t)N_STORE * 4);
    int* partials= (int*)alloc(512 * 4);
    int* cursor  = (int*)alloc((size_t)N_STORE * 4);
    u16* panelS[3]; u16* panelD[3];
    for (int l = 0; l < 3; ++l) {
        int KT = (l == 0) ? 4 : 2;
        panelS[l] = (u16*)alloc((size_t)KT * 9 * 64 * 8 * 2);
        panelD[l] = (u16*)alloc((size_t)KT * 5 * 64 * 8 * 2);
    }
    u16* projS  = (u16*)alloc((size_t)N_STORE * 144 * 2);  // 28.8 MB
    u16* projD  = (u16*)alloc((size_t)N_DEPT * 80 * 2);    //  3.2 MB
    u16* actSA  = (u16*)alloc((size_t)N_STORE * 64 * 2);   // 12.8 MB (l0 out)
    u16* actDA  = (u16*)alloc((size_t)N_DEPT * 64 * 2);
    u16* actSB  = (u16*)alloc((size_t)N_STORE * 64 * 2);   // 12.8 MB (l1 out)
    u16* actDB  = (u16*)alloc((size_t)N_DEPT * 64 * 2);

    float* outStoreF = (float*)d_out;                       // final output: FLOAT32
    float* outDeptF  = outStoreF + (size_t)N_STORE * 64;

    // ---- CSR build per relation (block [src;dst] int32, dict slots — HW-verified) ----
    struct Rel { const int* e; int ndst; int* offs; int* ss; };
    Rel rels[3] = {
        {e_sd, N_DEPT,  off_sd, srcs_sd},
        {e_ds, N_STORE, off_ds, srcs_ds},
        {e_ss, N_STORE, off_ss, srcs_ss},
    };
    int ebl = (E + 255) / 256;
    for (int r = 0; r < 3; ++r) {
        int n = rels[r].ndst;
        int nb1 = (n + 255) / 256;
        k_zeroi<<<nb1, 256, 0, stream>>>(counts, n);
        k_hist<<<ebl, 256, 0, stream>>>(rels[r].e, E, n, counts);
        k_scan1<<<nb1, 256, 0, stream>>>(counts, n, incl, partials);
        k_scan2<<<1, 512, 0, stream>>>(partials, nb1);
        k_scan3<<<nb1, 256, 0, stream>>>(counts, incl, partials, n, E, rels[r].offs, cursor);
        k_scatter<<<ebl, 256, 0, stream>>>(rels[r].e, E, n, cursor, rels[r].ss);
    }

    // ---- layers ----
    for (int l = 0; l < 3; ++l) {
        int K = (l == 0) ? 128 : 64;
        const float *Ws[3], *Wd[3], *aS[3], *aD[3];
        for (int rr = 0; rr < 3; ++rr) {
            Ws[rr] = (l == 0) ? W_src0 + (size_t)rr * 128 * 64
                              : W_src_h + (size_t)((l - 1) * 3 + rr) * 64 * 64;
            Wd[rr] = (l == 0) ? W_dst0 + (size_t)rr * 128 * 64
                              : W_dst_h + (size_t)((l - 1) * 3 + rr) * 64 * 64;
            aS[rr] = att_src + (size_t)(l * 3 + rr) * 64;
            aD[rr] = att_dst + (size_t)(l * 3 + rr) * 64;
        }
        k_pack_store<<<(K * 144 + 255) / 256, 256, 0, stream>>>(
            Ws[0], Ws[2], Wd[1], Wd[2], aS[0], aS[2], aD[1], aD[2], K, panelS[l]);
        k_pack_dept<<<(K * 80 + 255) / 256, 256, 0, stream>>>(
            Ws[1], Wd[0], aD[0], aS[1], K, panelD[l]);

        int gbS = (N_STORE / 16 * 64 + 255) / 256;
        int gbD = (N_DEPT / 16 * 64 + 255) / 256;
        if (l == 0) {
            k_gemm<4, 1><<<gbS, 256, 0, stream>>>(x_store, N_STORE, K, panelS[l], 9, projS, 144);
            k_gemm<4, 1><<<gbD, 256, 0, stream>>>(x_dept, N_DEPT, K, panelD[l], 5, projD, 80);
        } else if (l == 1) {
            k_gemm<2, 0><<<gbS, 256, 0, stream>>>(actSA, N_STORE, K, panelS[l], 9, projS, 144);
            k_gemm<2, 0><<<gbD, 256, 0, stream>>>(actDA, N_DEPT, K, panelD[l], 5, projD, 80);
        } else {
            k_gemm<2, 0><<<gbS, 256, 0, stream>>>(actSB, N_STORE, K, panelS[l], 9, projS, 144);
            k_gemm<2, 0><<<gbD, 256, 0, stream>>>(actDB, N_DEPT, K, panelD[l], 5, projD, 80);
        }

        int relu = (l < 2) ? 1 : 0;
        u16* bS = (l == 0) ? actSA : actSB;     // bf16 targets for l0/l1
        u16* bD = (l == 0) ? actDA : actDB;
        float* fS = (l == 2) ? outStoreF : nullptr;   // f32 targets for l2 (d_out)
        float* fD = (l == 2) ? outDeptF  : nullptr;
        // r0: store -> dept (final write)
        k_agg<<<N_DEPT / 4, 256, 0, stream>>>(
            off_sd, srcs_sd, N_DEPT, N_STORE,
            projS, 144, 0, 128,
            projD, 80, 64,
            bias + (size_t)(l * 3 + 0) * 64, 1.0f, 1, relu, bD, fD);
        // r1: dept -> store (partial, scaled 0.5, no relu)
        k_agg<<<N_STORE / 4, 256, 0, stream>>>(
            off_ds, srcs_ds, N_STORE, N_DEPT,
            projD, 80, 0, 68,
            projS, 144, 136,
            bias + (size_t)(l * 3 + 1) * 64, 0.5f, 0, 0, bS, fS);
        // r2: store -> store (add partial, relu, final write)
        k_agg<<<N_STORE / 4, 256, 0, stream>>>(
            off_ss, srcs_ss, N_STORE, N_STORE,
            projS, 144, 64, 132,
            projS, 144, 140,
            bias + (size_t)(l * 3 + 2) * 64, 0.5f, 2, relu, bS, fS);
    }
    (void)n_in; (void)out_size; (void)ws_size;
}

// Round 9
// 1105.884 us; speedup vs baseline: 1.4198x; 1.4198x over previous
//
#include <hip/hip_runtime.h>
#include <hip/hip_bf16.h>

#define N_STORE 100000
#define N_DEPT  20000
#define F_IN    128

using u16    = unsigned short;
using bf16x8 = __attribute__((ext_vector_type(8))) __bf16;
using f32x4  = __attribute__((ext_vector_type(4))) float;

__device__ __forceinline__ float b2f(u16 x) {
    unsigned u = ((unsigned)x) << 16;
    return __builtin_bit_cast(float, u);
}
__device__ __forceinline__ u16 f2b(float f) {
    unsigned u = __builtin_bit_cast(unsigned, f);
    u += 0x7FFFu + ((u >> 16) & 1u);   // round-to-nearest-even
    return (u16)(u >> 16);
}

// ---------------- CSR build (edges: int32, block [src(E); dst(E)], dict slots — HW-verified r7) ----
__global__ void k_zeroi(int* p, int n) {
    int i = blockIdx.x * 256 + threadIdx.x;
    if (i < n) p[i] = 0;
}

__global__ void k_hist(const int* __restrict__ e, int E, int n, int* __restrict__ counts) {
    int i = blockIdx.x * 256 + threadIdx.x;
    if (i >= E) return;
    int d = e[E + i];
    if (d >= 0 && d < n) atomicAdd(&counts[d], 1);
}

__global__ void k_scan1(const int* __restrict__ counts, int n,
                        int* __restrict__ incl, int* __restrict__ partials) {
    __shared__ int s[256];
    int t = threadIdx.x, i = blockIdx.x * 256 + t;
    int v = (i < n) ? counts[i] : 0;
    s[t] = v; __syncthreads();
    for (int o = 1; o < 256; o <<= 1) {
        int u = (t >= o) ? s[t - o] : 0;
        __syncthreads();
        s[t] += u;
        __syncthreads();
    }
    if (i < n) incl[i] = s[t];
    if (t == 255) partials[blockIdx.x] = s[255];
}

__global__ void k_scan2(int* partials, int nb) {
    __shared__ int s[512];
    int t = threadIdx.x;
    int v = (t < nb) ? partials[t] : 0;
    s[t] = v; __syncthreads();
    for (int o = 1; o < 512; o <<= 1) {
        int u = (t >= o) ? s[t - o] : 0;
        __syncthreads();
        s[t] += u;
        __syncthreads();
    }
    if (t < nb) partials[t] = s[t];
}

__global__ void k_scan3(const int* __restrict__ counts, const int* __restrict__ incl,
                        const int* __restrict__ partials, int n, int total,
                        int* __restrict__ offs, int* __restrict__ cursor) {
    int i = blockIdx.x * 256 + threadIdx.x;
    if (i < n) {
        int base = blockIdx.x ? partials[blockIdx.x - 1] : 0;
        int e = base + incl[i] - counts[i];
        offs[i] = e;
        cursor[i] = e;
    } else if (i == n) {
        offs[n] = total;
    }
}

__global__ void k_scatter(const int* __restrict__ e, int E, int n,
                          int* __restrict__ cursor, int* __restrict__ srcs_sorted) {
    int i = blockIdx.x * 256 + threadIdx.x;
    if (i >= E) return;
    int d = e[E + i];
    if (d < 0 || d >= n) return;
    int pos = atomicAdd(&cursor[d], 1);
    srcs_sorted[pos] = e[i];
}

// ---------------- weight panel packing (MFMA B-fragment order), f32 -> bf16 ----
__global__ void k_pack_store(const float* __restrict__ Wa, const float* __restrict__ Wb,
                             const float* __restrict__ Wd1, const float* __restrict__ Wd2,
                             const float* __restrict__ aS0, const float* __restrict__ aS2,
                             const float* __restrict__ aD1, const float* __restrict__ aD2,
                             int K, u16* __restrict__ out) {
    int id = blockIdx.x * 256 + threadIdx.x;
    int total = K * 144;
    if (id >= total) return;
    int k = id / 144, n = id - k * 144;
    float val;
    if (n < 64) val = Wa[k * 64 + n];
    else if (n < 128) val = Wb[k * 64 + (n - 64)];
    else {
        int g = (n - 128) >> 2, h = (n - 128) & 3;
        const float* W = (g == 0) ? Wa : (g == 1) ? Wb : (g == 2) ? Wd1 : Wd2;
        const float* a = (g == 0) ? aS0 : (g == 1) ? aS2 : (g == 2) ? aD1 : aD2;
        float acc = 0.f;
        for (int c = 0; c < 16; ++c) acc += W[k * 64 + h * 16 + c] * a[h * 16 + c];
        val = acc;
    }
    int KT = K >> 5;
    int ct = n >> 4, col = n & 15, kt = k >> 5, q = (k >> 3) & 3, j = k & 7;
    out[(size_t)((ct * KT + kt) * 64 + q * 16 + col) * 8 + j] = f2b(val);
}

__global__ void k_pack_dept(const float* __restrict__ Ws1, const float* __restrict__ Wd0,
                            const float* __restrict__ aD0, const float* __restrict__ aS1,
                            int K, u16* __restrict__ out) {
    int id = blockIdx.x * 256 + threadIdx.x;
    int total = K * 80;
    if (id >= total) return;
    int k = id / 80, n = id - k * 80;
    float val;
    if (n < 64) val = Ws1[k * 64 + n];
    else if (n < 72) {
        int g = (n - 64) >> 2, h = (n - 64) & 3;
        const float* W = g ? Ws1 : Wd0;
        const float* a = g ? aS1 : aD0;
        float acc = 0.f;
        for (int c = 0; c < 16; ++c) acc += W[k * 64 + h * 16 + c] * a[h * 16 + c];
        val = acc;
    } else val = 0.f;
    int KT = K >> 5;
    int ct = n >> 4, col = n & 15, kt = k >> 5, q = (k >> 3) & 3, j = k & 7;
    out[(size_t)((ct * KT + kt) * 64 + q * 16 + col) * 8 + j] = f2b(val);
}

// ---------------- GEMM: wave per 16-row stripe, bf16 out; CVT=1 reads f32 A ----
template <int KT, int CVT>
__global__ void k_gemm(const void* __restrict__ Ain, int nrows, int K,
                       const u16* __restrict__ Bpanel, int CT,
                       u16* __restrict__ C, int cstride) {
    int wid = (blockIdx.x * blockDim.x + threadIdx.x) >> 6;
    int lane = threadIdx.x & 63;
    int m0 = wid << 4;
    if (m0 >= nrows) return;
    int r = lane & 15, q = lane >> 4;
    bf16x8 a[KT];
    if (CVT) {
        const float* ap = (const float*)Ain + (size_t)(m0 + r) * K + q * 8;
#pragma unroll
        for (int kt = 0; kt < KT; ++kt) {
            f32x4 f0 = *(const f32x4*)(ap + kt * 32);
            f32x4 f1 = *(const f32x4*)(ap + kt * 32 + 4);
            bf16x8 v;
#pragma unroll
            for (int j = 0; j < 4; ++j) {
                v[j]     = __builtin_bit_cast(__bf16, f2b(f0[j]));
                v[4 + j] = __builtin_bit_cast(__bf16, f2b(f1[j]));
            }
            a[kt] = v;
        }
    } else {
        const u16* ap = (const u16*)Ain + (size_t)(m0 + r) * K + q * 8;
#pragma unroll
        for (int kt = 0; kt < KT; ++kt) a[kt] = *(const bf16x8*)(ap + kt * 32);
    }
    const bf16x8* B = (const bf16x8*)Bpanel;
    for (int ct = 0; ct < CT; ++ct) {
        f32x4 acc = {0.f, 0.f, 0.f, 0.f};
#pragma unroll
        for (int kt = 0; kt < KT; ++kt)
            acc = __builtin_amdgcn_mfma_f32_16x16x32_bf16(a[kt], B[(ct * KT + kt) * 64 + lane], acc, 0, 0, 0);
        u16* cp = C + (size_t)m0 * cstride + ct * 16 + r;
#pragma unroll
        for (int i = 0; i < 4; ++i) cp[(size_t)(q * 4 + i) * cstride] = f2b(acc[i]);
    }
}

// ---------------- batched CSR-row aggregation helper (deep MLP) ----------------
// Issues UB index loads + 2*UB row loads before consuming: ~4-8x more loads in flight.
template <int UB>
__device__ __forceinline__ void agg_row(const int* __restrict__ srcs, int j0, int j1, int nsrcmax,
                                        const u16* __restrict__ tab, int stride, int hsOff, int alsOff,
                                        int lane, int h, float ald,
                                        float& acc, float& den) {
    for (int j = j0; j < j1; ) {
        int nb = j1 - j; nb = nb > UB ? UB : nb;
        int s[UB];
#pragma unroll
        for (int k = 0; k < UB; ++k) {
            int sv = srcs[j + (k < nb ? k : 0)];
            s[k] = (sv < 0 || sv >= nsrcmax) ? 0 : sv;
        }
        float av[UB], hv[UB];
#pragma unroll
        for (int k = 0; k < UB; ++k) {
            const u16* row = tab + (size_t)s[k] * stride;
            av[k] = b2f(row[alsOff + h]);
            hv[k] = b2f(row[hsOff + lane]);
        }
#pragma unroll
        for (int k = 0; k < UB; ++k) {
            if (k < nb) {
                float e = av[k] + ald;
                e = (e > 0.f) ? e : 0.2f * e;
                float ex = __expf(e);
                acc = fmaf(ex, hv[k], acc);
                den += ex;
            }
        }
        j += nb;
    }
}

// ---------------- r0: store -> dept, single relation, final write ----------------
__global__ void k_agg1(const int* __restrict__ offs, const int* __restrict__ srcs, int ndst,
                       int nsrcmax,
                       const u16* __restrict__ srcTab, int sstride, int hsOff, int alsOff,
                       const u16* __restrict__ dstTab, int dstride, int aldOff,
                       const float* __restrict__ bias, int doRelu,
                       u16* __restrict__ bOut, float* __restrict__ fOut) {
    int wid = (blockIdx.x * blockDim.x + threadIdx.x) >> 6;
    if (wid >= ndst) return;
    int lane = threadIdx.x & 63, h = lane >> 4;
    float ald = b2f(dstTab[(size_t)wid * dstride + aldOff + h]);
    float acc = 0.f, den = 0.f;
    agg_row<8>(srcs, offs[wid], offs[wid + 1], nsrcmax,
               srcTab, sstride, hsOff, alsOff, lane, h, ald, acc, den);
    float out = acc / (den + 1e-16f) + bias[lane];
    if (doRelu) out = out > 0.f ? out : 0.f;
    size_t oi = (size_t)wid * 64 + lane;
    if (fOut) fOut[oi] = out;
    else      bOut[oi] = f2b(out);
}

// ---------------- fused r1+r2: dept->store + store->store, single write ----------------
__global__ void k_agg2(const int* __restrict__ offs1, const int* __restrict__ srcs1,
                       const int* __restrict__ offs2, const int* __restrict__ srcs2,
                       const u16* __restrict__ projD, const u16* __restrict__ projS,
                       const float* __restrict__ bias1, const float* __restrict__ bias2,
                       int doRelu,
                       u16* __restrict__ bOut, float* __restrict__ fOut) {
    int wid = (blockIdx.x * blockDim.x + threadIdx.x) >> 6;
    if (wid >= N_STORE) return;
    int lane = threadIdx.x & 63, h = lane >> 4;
    const u16* myrow = projS + (size_t)wid * 144;
    float ald1 = b2f(myrow[136 + h]);          // att_dst fold, relation 1
    float ald2 = b2f(myrow[140 + h]);          // att_dst fold, relation 2
    float a1 = 0.f, d1 = 0.f, a2 = 0.f, d2 = 0.f;
    // r1: gather dept rows (stride 80, hs 0, als 68)
    agg_row<4>(srcs1, offs1[wid], offs1[wid + 1], N_DEPT,
               projD, 80, 0, 68, lane, h, ald1, a1, d1);
    // r2: gather store rows (stride 144, hs 64, als 132)
    agg_row<4>(srcs2, offs2[wid], offs2[wid + 1], N_STORE,
               projS, 144, 64, 132, lane, h, ald2, a2, d2);
    float out = (a1 / (d1 + 1e-16f) + bias1[lane] + a2 / (d2 + 1e-16f) + bias2[lane]) * 0.5f;
    if (doRelu) out = out > 0.f ? out : 0.f;
    size_t oi = (size_t)wid * 64 + lane;
    if (fOut) fOut[oi] = out;
    else      bOut[oi] = f2b(out);
}

extern "C" void kernel_launch(void* const* d_in, const int* in_sizes, int n_in,
                              void* d_out, int out_size, void* d_ws, size_t ws_size,
                              hipStream_t stream) {
    const float* x_store = (const float*)d_in[0];
    const float* x_dept  = (const float*)d_in[1];
    const int* e_sd = (const int*)d_in[2];
    const int* e_ds = (const int*)d_in[3];
    const int* e_ss = (const int*)d_in[4];
    const float* W_src0  = (const float*)d_in[5];
    const float* W_dst0  = (const float*)d_in[6];
    const float* W_src_h = (const float*)d_in[7];
    const float* W_dst_h = (const float*)d_in[8];
    const float* att_src = (const float*)d_in[9];
    const float* att_dst = (const float*)d_in[10];
    const float* bias    = (const float*)d_in[11];
    const int E = in_sizes[2] / 2;

    // ---- workspace (~77 MB) ----
    char* w = (char*)d_ws;
    auto alloc = [&](size_t bytes) -> char* {
        char* p = w;
        w += (bytes + 255) & ~(size_t)255;
        return p;
    };
    int* off_sd  = (int*)alloc((size_t)(N_DEPT + 1) * 4);
    int* off_ds  = (int*)alloc((size_t)(N_STORE + 1) * 4);
    int* off_ss  = (int*)alloc((size_t)(N_STORE + 1) * 4);
    int* srcs_sd = (int*)alloc((size_t)E * 4);
    int* srcs_ds = (int*)alloc((size_t)E * 4);
    int* srcs_ss = (int*)alloc((size_t)E * 4);
    int* counts  = (int*)alloc((size_t)N_STORE * 4);
    int* incl    = (int*)alloc((size_t)N_STORE * 4);
    int* partials= (int*)alloc(512 * 4);
    int* cursor  = (int*)alloc((size_t)N_STORE * 4);
    u16* panelS[3]; u16* panelD[3];
    for (int l = 0; l < 3; ++l) {
        int KT = (l == 0) ? 4 : 2;
        panelS[l] = (u16*)alloc((size_t)KT * 9 * 64 * 8 * 2);
        panelD[l] = (u16*)alloc((size_t)KT * 5 * 64 * 8 * 2);
    }
    u16* projS  = (u16*)alloc((size_t)N_STORE * 144 * 2);
    u16* projD  = (u16*)alloc((size_t)N_DEPT * 80 * 2);
    u16* actSA  = (u16*)alloc((size_t)N_STORE * 64 * 2);
    u16* actDA  = (u16*)alloc((size_t)N_DEPT * 64 * 2);
    u16* actSB  = (u16*)alloc((size_t)N_STORE * 64 * 2);
    u16* actDB  = (u16*)alloc((size_t)N_DEPT * 64 * 2);

    float* outStoreF = (float*)d_out;                       // final output: f32
    float* outDeptF  = outStoreF + (size_t)N_STORE * 64;

    // ---- CSR build per relation ----
    struct Rel { const int* e; int ndst; int* offs; int* ss; };
    Rel rels[3] = {
        {e_sd, N_DEPT,  off_sd, srcs_sd},
        {e_ds, N_STORE, off_ds, srcs_ds},
        {e_ss, N_STORE, off_ss, srcs_ss},
    };
    int ebl = (E + 255) / 256;
    for (int r = 0; r < 3; ++r) {
        int n = rels[r].ndst;
        int nb1 = (n + 255) / 256;
        k_zeroi<<<nb1, 256, 0, stream>>>(counts, n);
        k_hist<<<ebl, 256, 0, stream>>>(rels[r].e, E, n, counts);
        k_scan1<<<nb1, 256, 0, stream>>>(counts, n, incl, partials);
        k_scan2<<<1, 512, 0, stream>>>(partials, nb1);
        k_scan3<<<nb1, 256, 0, stream>>>(counts, incl, partials, n, E, rels[r].offs, cursor);
        k_scatter<<<ebl, 256, 0, stream>>>(rels[r].e, E, n, cursor, rels[r].ss);
    }

    // ---- layers ----
    for (int l = 0; l < 3; ++l) {
        int K = (l == 0) ? 128 : 64;
        const float *Ws[3], *Wd[3], *aS[3], *aD[3];
        for (int rr = 0; rr < 3; ++rr) {
            Ws[rr] = (l == 0) ? W_src0 + (size_t)rr * 128 * 64
                              : W_src_h + (size_t)((l - 1) * 3 + rr) * 64 * 64;
            Wd[rr] = (l == 0) ? W_dst0 + (size_t)rr * 128 * 64
                              : W_dst_h + (size_t)((l - 1) * 3 + rr) * 64 * 64;
            aS[rr] = att_src + (size_t)(l * 3 + rr) * 64;
            aD[rr] = att_dst + (size_t)(l * 3 + rr) * 64;
        }
        k_pack_store<<<(K * 144 + 255) / 256, 256, 0, stream>>>(
            Ws[0], Ws[2], Wd[1], Wd[2], aS[0], aS[2], aD[1], aD[2], K, panelS[l]);
        k_pack_dept<<<(K * 80 + 255) / 256, 256, 0, stream>>>(
            Ws[1], Wd[0], aD[0], aS[1], K, panelD[l]);

        int gbS = (N_STORE / 16 * 64 + 255) / 256;
        int gbD = (N_DEPT / 16 * 64 + 255) / 256;
        if (l == 0) {
            k_gemm<4, 1><<<gbS, 256, 0, stream>>>(x_store, N_STORE, K, panelS[l], 9, projS, 144);
            k_gemm<4, 1><<<gbD, 256, 0, stream>>>(x_dept, N_DEPT, K, panelD[l], 5, projD, 80);
        } else if (l == 1) {
            k_gemm<2, 0><<<gbS, 256, 0, stream>>>(actSA, N_STORE, K, panelS[l], 9, projS, 144);
            k_gemm<2, 0><<<gbD, 256, 0, stream>>>(actDA, N_DEPT, K, panelD[l], 5, projD, 80);
        } else {
            k_gemm<2, 0><<<gbS, 256, 0, stream>>>(actSB, N_STORE, K, panelS[l], 9, projS, 144);
            k_gemm<2, 0><<<gbD, 256, 0, stream>>>(actDB, N_DEPT, K, panelD[l], 5, projD, 80);
        }

        int relu = (l < 2) ? 1 : 0;
        u16* bS = (l == 0) ? actSA : actSB;
        u16* bD = (l == 0) ? actDA : actDB;
        float* fS = (l == 2) ? outStoreF : nullptr;
        float* fD = (l == 2) ? outDeptF  : nullptr;
        // r0: store -> dept (final write)
        k_agg1<<<N_DEPT / 4, 256, 0, stream>>>(
            off_sd, srcs_sd, N_DEPT, N_STORE,
            projS, 144, 0, 128,
            projD, 80, 64,
            bias + (size_t)(l * 3 + 0) * 64, relu, bD, fD);
        // fused r1+r2 -> store output (single write)
        k_agg2<<<N_STORE / 4, 256, 0, stream>>>(
            off_ds, srcs_ds, off_ss, srcs_ss,
            projD, projS,
            bias + (size_t)(l * 3 + 1) * 64, bias + (size_t)(l * 3 + 2) * 64,
            relu, bS, fS);
    }
    (void)n_in; (void)out_size; (void)ws_size;
}